// Round 1
// baseline (911.899 us; speedup 1.0000x reference)
//
#include <hip/hip_runtime.h>

#define DI __device__ __forceinline__

typedef unsigned short u16t;
typedef u16t u16x4 __attribute__((ext_vector_type(4)));
typedef u16t u16x8 __attribute__((ext_vector_type(8)));

static constexpr int PLANE = 256 * 256 * 64;   // elements per batch image
static constexpr double PI = 3.14159265358979323846264338327950288;

DI float us2f(u16t u) {
  union { unsigned int i; float f; } v; v.i = ((unsigned int)u) << 16; return v.f;
}
DI u16t f2us(float f) {            // f32 -> bf16 bits, round-to-nearest-even
  union { float f; unsigned int i; } v; v.f = f;
  unsigned int r = v.i + 0x7FFFu + ((v.i >> 16) & 1u);
  return (u16t)(r >> 16);
}
DI float gelu(float x) { return 0.5f * x * (1.0f + erff(x * 0.70710678118654752f)); }

// ---------------- init: DCT matrices + transposed 1x1 conv weights ----------
__global__ void k_init(float* __restrict__ FT, float* __restrict__ IT,
                       float* __restrict__ w1t, float* __restrict__ w2t,
                       const float* __restrict__ c1a, const float* __restrict__ c2w)
{
  const int blk = blockIdx.x, t = threadIdx.x;
  if (blk < 256) {            // FT[n][k] = 2 cos(pi (2n+1) k / 512)
    double ang = PI * (2.0 * blk + 1.0) * (double)t / 512.0;
    FT[blk * 256 + t] = (float)(2.0 * cos(ang));
  } else if (blk < 512) {     // IT[k][n] = w_k cos(pi (2n+1) k / 512) / 256
    int k = blk - 256;
    double wk = (k == 0) ? 0.5 : 1.0;
    double ang = PI * (2.0 * t + 1.0) * (double)k / 512.0;
    IT[k * 256 + t] = (float)(wk * cos(ang) / 256.0);
  } else if (blk == 512) {    // w1t[ci][co] = c1a[co][ci]
    for (int i = 0; i < 16; ++i) { int e = i * 256 + t; w1t[e] = c1a[(e & 63) * 64 + (e >> 6)]; }
  } else {
    for (int i = 0; i < 16; ++i) { int e = i * 256 + t; w2t[e] = c2w[(e & 63) * 64 + (e >> 6)]; }
  }
}

// ---------------- 1-D transform along one spatial axis ----------------------
// out[b, other, ko, c] = sum_n mat[n][ko] * in[b, other, n, c]
// where "row" axis (n / ko) has element stride s_row, the fixed axis s_other.
template<bool INBF, bool OUTBF>
__global__ __launch_bounds__(256) void k_transform(const void* __restrict__ inv,
    void* __restrict__ outv, const float* __restrict__ mat,
    const int s_other, const int s_row)
{
  __shared__ __align__(16) float xs[64][68];
  const int t = threadIdx.x;
  const int b = blockIdx.x >> 8, other = blockIdx.x & 255;
  const size_t base = (size_t)b * PLANE + (size_t)other * (size_t)s_other;
  const int kg = t >> 3, cg = t & 7;      // thread: 8 output rows x 8 channels
  float acc[8][8];
#pragma unroll
  for (int i = 0; i < 8; ++i)
#pragma unroll
    for (int j = 0; j < 8; ++j) acc[i][j] = 0.0f;

  const int srow = t >> 4, scol = (t & 15) * 4;
  for (int chunk = 0; chunk < 4; ++chunk) {
    __syncthreads();
#pragma unroll
    for (int p = 0; p < 4; ++p) {
      const int row = srow + p * 16;
      const size_t src = base + (size_t)(chunk * 64 + row) * (size_t)s_row + scol;
      float4 v;
      if constexpr (INBF) {
        u16x4 u = *(const u16x4*)((const u16t*)inv + src);
        v.x = us2f(u[0]); v.y = us2f(u[1]); v.z = us2f(u[2]); v.w = us2f(u[3]);
      } else {
        v = *(const float4*)((const float*)inv + src);
      }
      *(float4*)&xs[row][scol] = v;
    }
    __syncthreads();
#pragma unroll 4
    for (int w = 0; w < 64; ++w) {
      const float* mp = mat + (chunk * 64 + w) * 256 + kg * 8;
      float mv[8], xv[8];
      *(float4*)&mv[0] = *(const float4*)mp;
      *(float4*)&mv[4] = *(const float4*)(mp + 4);
      *(float4*)&xv[0] = *(const float4*)&xs[w][cg * 8];
      *(float4*)&xv[4] = *(const float4*)&xs[w][cg * 8 + 4];
#pragma unroll
      for (int i = 0; i < 8; ++i)
#pragma unroll
        for (int j = 0; j < 8; ++j) acc[i][j] = fmaf(mv[i], xv[j], acc[i][j]);
    }
  }
#pragma unroll
  for (int i = 0; i < 8; ++i) {
    const size_t o = base + (size_t)(kg * 8 + i) * (size_t)s_row + cg * 8;
    if constexpr (OUTBF) {
      u16x8 u;
#pragma unroll
      for (int j = 0; j < 8; ++j) u[j] = f2us(acc[i][j]);
      *(u16x8*)((u16t*)outv + o) = u;
    } else {
      float* op = (float*)outv + o;
      float4 v0, v1;
      v0.x = acc[i][0]; v0.y = acc[i][1]; v0.z = acc[i][2]; v0.w = acc[i][3];
      v1.x = acc[i][4]; v1.y = acc[i][5]; v1.z = acc[i][6]; v1.w = acc[i][7];
      *(float4*)op = v0; *(float4*)(op + 4) = v1;
    }
  }
}

// ---------------- c1a: y1 = gelu(x @ w1t), pixelwise 64x64 GEMM -------------
__global__ __launch_bounds__(256) void k_conv1(const u16t* __restrict__ xin,
    u16t* __restrict__ yout, const float* __restrict__ w1t)
{
  __shared__ __align__(16) u16t xsT[64][264];   // transposed [c][px]
  const int t = threadIdx.x;
  const size_t ebase = (size_t)blockIdx.x * 16384;  // 256 px * 64 c
#pragma unroll
  for (int q = 0; q < 16; ++q) {
    const int e4 = q * 1024 + t * 4;
    const int px = e4 >> 6, c = e4 & 63;
    u16x4 u = *(const u16x4*)(xin + ebase + e4);
    xsT[c + 0][px] = u[0]; xsT[c + 1][px] = u[1];
    xsT[c + 2][px] = u[2]; xsT[c + 3][px] = u[3];
  }
  __syncthreads();
  const int pxg = t >> 3, cg = t & 7;
  float acc[8][8];
#pragma unroll
  for (int i = 0; i < 8; ++i)
#pragma unroll
    for (int j = 0; j < 8; ++j) acc[i][j] = 0.0f;
#pragma unroll 4
  for (int k = 0; k < 64; ++k) {
    u16x8 xu = *(const u16x8*)&xsT[k][pxg * 8];
    float xv[8];
#pragma unroll
    for (int i = 0; i < 8; ++i) xv[i] = us2f(xu[i]);
    const float* wp = w1t + k * 64 + cg * 8;
    float wv[8];
    *(float4*)&wv[0] = *(const float4*)wp;
    *(float4*)&wv[4] = *(const float4*)(wp + 4);
#pragma unroll
    for (int i = 0; i < 8; ++i)
#pragma unroll
      for (int j = 0; j < 8; ++j) acc[i][j] = fmaf(xv[i], wv[j], acc[i][j]);
  }
#pragma unroll
  for (int i = 0; i < 8; ++i) {
    u16x8 u;
#pragma unroll
    for (int j = 0; j < 8; ++j) u[j] = f2us(gelu(acc[i][j]));
    *(u16x8*)(yout + ebase + (size_t)(pxg * 8 + i) * 64 + cg * 8) = u;
  }
}

// ---------------- attention branch: 4 blocks (8x8) per WG -------------------
DI size_t gaddr(int nb, int mm) {
  const int b = nb >> 10, r = nb & 1023, bh = r >> 5, bw = r & 31;
  const int i = mm >> 3, j = mm & 7;
  return ((size_t)((b * 256 + bh * 8 + i) * 256 + bw * 8 + j)) * 64;
}

__global__ __launch_bounds__(256) void k_attn(const u16t* __restrict__ xdct,
    float* __restrict__ xlow, const float* __restrict__ Wq,
    const float* __restrict__ Wk, const float* __restrict__ Wv,
    const float* __restrict__ resc, const float* __restrict__ pw,
    const float* __restrict__ pb)
{
  __shared__ __align__(16) u16t XT[64][264];   // X transposed [c][px]; reused as X1T
  __shared__ __align__(16) u16t QT[64][264], KT[64][264], VT[64][264];
  __shared__ float attnS[4][16][16];
  __shared__ float qn[4][64], kn[4][64];
  const int t = threadIdx.x;
  const int nb0 = blockIdx.x * 4;
  // stage X (4 blocks x 64 mm x 64 c), transposed
#pragma unroll
  for (int q = 0; q < 16; ++q) {
    const int e4 = q * 1024 + t * 4;
    const int px = e4 >> 6, c = e4 & 63;
    const size_t g = gaddr(nb0 + (px >> 6), px & 63) + c;
    u16x4 u = *(const u16x4*)(xdct + g);
    XT[c + 0][px] = u[0]; XT[c + 1][px] = u[1];
    XT[c + 2][px] = u[2]; XT[c + 3][px] = u[3];
  }
  __syncthreads();
  const int pxg = t >> 3, cg = t & 7;

  auto gemmW = [&](const float* __restrict__ W, u16t (&DST)[64][264]) {
    float acc[8][8];
#pragma unroll
    for (int i = 0; i < 8; ++i)
#pragma unroll
      for (int j = 0; j < 8; ++j) acc[i][j] = 0.0f;
#pragma unroll 4
    for (int k = 0; k < 64; ++k) {
      u16x8 xu = *(const u16x8*)&XT[k][pxg * 8];
      float xv[8];
#pragma unroll
      for (int i = 0; i < 8; ++i) xv[i] = us2f(xu[i]);
      const float* wp = W + k * 64 + cg * 8;
      float wv[8];
      *(float4*)&wv[0] = *(const float4*)wp;
      *(float4*)&wv[4] = *(const float4*)(wp + 4);
#pragma unroll
      for (int i = 0; i < 8; ++i)
#pragma unroll
        for (int j = 0; j < 8; ++j) acc[i][j] = fmaf(xv[i], wv[j], acc[i][j]);
    }
#pragma unroll
    for (int i = 0; i < 8; ++i)
#pragma unroll
      for (int j = 0; j < 8; ++j) DST[cg * 8 + j][pxg * 8 + i] = f2us(acc[i][j]);
  };
  gemmW(Wq, QT);
  gemmW(Wk, KT);
  gemmW(Wv, VT);
  __syncthreads();
  // column L2 norms of Q and K (per block, per channel)
  {
    const int b4 = t >> 6, c = t & 63;
    float sq = 0.0f, sk = 0.0f;
    for (int m = 0; m < 64; ++m) {
      float a = us2f(QT[c][b4 * 64 + m]); sq = fmaf(a, a, sq);
      float bb = us2f(KT[c][b4 * 64 + m]); sk = fmaf(bb, bb, sk);
    }
    qn[b4][c] = 1.0f / fmaxf(sqrtf(sq), 1e-12f);
    kn[b4][c] = 1.0f / fmaxf(sqrtf(sk), 1e-12f);
  }
  __syncthreads();
  // per-wave: one 8x8 block, loop over 4 heads
  const int wv4 = t >> 6, l = t & 63;
  const int d = l & 15, eb = l >> 4, mb = wv4 * 64;
  for (int h = 0; h < 4; ++h) {
    const int ch = h * 16;
    float a[4] = {0.f, 0.f, 0.f, 0.f};
    for (int m = 0; m < 64; ++m) {
      float qv = us2f(QT[ch + d][mb + m]);
#pragma unroll
      for (int p = 0; p < 4; ++p)
        a[p] = fmaf(qv, us2f(KT[ch + eb * 4 + p][mb + m]), a[p]);
    }
    const float iq = qn[wv4][ch + d] * resc[h];
#pragma unroll
    for (int p = 0; p < 4; ++p) a[p] *= iq * kn[wv4][ch + eb * 4 + p];
    float mx = fmaxf(fmaxf(a[0], a[1]), fmaxf(a[2], a[3]));
    mx = fmaxf(mx, __shfl_xor(mx, 16)); mx = fmaxf(mx, __shfl_xor(mx, 32));
    float s = 0.0f;
#pragma unroll
    for (int p = 0; p < 4; ++p) { a[p] = expf(a[p] - mx); s += a[p]; }
    s += __shfl_xor(s, 16); s += __shfl_xor(s, 32);
    const float inv = 1.0f / s;
#pragma unroll
    for (int p = 0; p < 4; ++p) attnS[wv4][d][eb * 4 + p] = a[p] * inv;
    __syncthreads();
    // PV: lane = m; x1[m][ch+dd] = sum_e attn[dd][e] * v[e][m]
    {
      const int m = l;
      for (int dd = 0; dd < 16; ++dd) {
        float s2 = 0.0f;
#pragma unroll
        for (int e = 0; e < 16; ++e)
          s2 = fmaf(attnS[wv4][dd][e], us2f(VT[ch + e][mb + m]), s2);
        XT[ch + dd][mb + m] = f2us(s2);   // X1 transposed
      }
    }
    __syncthreads();
  }
  // proj: xlow[m][c'] = X1[m][:] @ pw + pb
  float acc[8][8];
#pragma unroll
  for (int i = 0; i < 8; ++i)
#pragma unroll
    for (int j = 0; j < 8; ++j) acc[i][j] = 0.0f;
#pragma unroll 4
  for (int k = 0; k < 64; ++k) {
    u16x8 xu = *(const u16x8*)&XT[k][pxg * 8];
    float xv[8];
#pragma unroll
    for (int i = 0; i < 8; ++i) xv[i] = us2f(xu[i]);
    const float* wp = pw + k * 64 + cg * 8;
    float wv[8];
    *(float4*)&wv[0] = *(const float4*)wp;
    *(float4*)&wv[4] = *(const float4*)(wp + 4);
#pragma unroll
    for (int i = 0; i < 8; ++i)
#pragma unroll
      for (int j = 0; j < 8; ++j) acc[i][j] = fmaf(xv[i], wv[j], acc[i][j]);
  }
  float bv[8];
  *(float4*)&bv[0] = *(const float4*)(pb + cg * 8);
  *(float4*)&bv[4] = *(const float4*)(pb + cg * 8 + 4);
#pragma unroll
  for (int i = 0; i < 8; ++i) {
    const int px = pxg * 8 + i;
    const size_t g = gaddr(nb0 + (px >> 6), px & 63) + cg * 8;
    float4 o0, o1;
    o0.x = acc[i][0] + bv[0]; o0.y = acc[i][1] + bv[1];
    o0.z = acc[i][2] + bv[2]; o0.w = acc[i][3] + bv[3];
    o1.x = acc[i][4] + bv[4]; o1.y = acc[i][5] + bv[5];
    o1.z = acc[i][6] + bv[6]; o1.w = acc[i][7] + bv[7];
    *(float4*)(xlow + g) = o0; *(float4*)(xlow + g + 4) = o1;
  }
}

// ------- depthwise 3x3 + gelu + residual + c2 GEMM + gelu + combine ---------
__global__ __launch_bounds__(256) void k_conv2(const u16t* __restrict__ y1,
    u16t* __restrict__ xio,             // xdct in, x_out (combined) out, in-place
    const float* __restrict__ xlow, const float* __restrict__ w2t,
    const float* __restrict__ dwg, const float* __restrict__ coef)
{
  __shared__ __align__(16) u16t y1h[18][18][68];
  __shared__ __align__(16) u16t xcT[64][264];
  __shared__ float dws[64][9];
  const int t = threadIdx.x;
  const int blk = blockIdx.x;
  const int b = blk >> 8, ty = (blk >> 4) & 15, tx = blk & 15;
  for (int e = t; e < 576; e += 256) dws[e / 9][e % 9] = dwg[e];
  // stage y1 tile with zero halo (16x16 interior, 18x18 staged)
  for (int s = t; s < 5184; s += 256) {
    const int r2 = s >> 4, c4 = (s & 15) * 4;
    const int iy2 = r2 / 18, ix2 = r2 % 18;
    const int py = ty * 16 + iy2 - 1, px = tx * 16 + ix2 - 1;
    u16x4 u = {0, 0, 0, 0};
    if ((unsigned)py < 256u && (unsigned)px < 256u) {
      const size_t g = ((size_t)((b * 256 + py) * 256 + px)) * 64 + c4;
      u = *(const u16x4*)(y1 + g);
    }
    y1h[iy2][ix2][c4 + 0] = u[0]; y1h[iy2][ix2][c4 + 1] = u[1];
    y1h[iy2][ix2][c4 + 2] = u[2]; y1h[iy2][ix2][c4 + 3] = u[3];
  }
  __syncthreads();
  // depthwise conv + gelu + residual -> xcT (transposed)
  {
    const int iy = t >> 4, ix = t & 15;
    const size_t gpx = ((size_t)((b * 256 + ty * 16 + iy) * 256 + tx * 16 + ix)) * 64;
    for (int c4 = 0; c4 < 64; c4 += 4) {
      float s0 = 0.f, s1 = 0.f, s2 = 0.f, s3 = 0.f;
#pragma unroll
      for (int dy = 0; dy < 3; ++dy)
#pragma unroll
        for (int dx = 0; dx < 3; ++dx) {
          const u16x4 u = *(const u16x4*)&y1h[iy + dy][ix + dx][c4];
          const int j = dy * 3 + dx;
          s0 = fmaf(us2f(u[0]), dws[c4 + 0][j], s0);
          s1 = fmaf(us2f(u[1]), dws[c4 + 1][j], s1);
          s2 = fmaf(us2f(u[2]), dws[c4 + 2][j], s2);
          s3 = fmaf(us2f(u[3]), dws[c4 + 3][j], s3);
        }
      const u16x4 x = *(const u16x4*)(xio + gpx + c4);
      xcT[c4 + 0][t] = f2us(gelu(s0) + us2f(x[0]));
      xcT[c4 + 1][t] = f2us(gelu(s1) + us2f(x[1]));
      xcT[c4 + 2][t] = f2us(gelu(s2) + us2f(x[2]));
      xcT[c4 + 3][t] = f2us(gelu(s3) + us2f(x[3]));
    }
  }
  __syncthreads();
  // c2 GEMM + gelu + residual + coef combine (+xdct), in-place into xio
  const int pxg = t >> 3, cg = t & 7;
  float acc[8][8];
#pragma unroll
  for (int i = 0; i < 8; ++i)
#pragma unroll
    for (int j = 0; j < 8; ++j) acc[i][j] = 0.0f;
#pragma unroll 4
  for (int k = 0; k < 64; ++k) {
    u16x8 xu = *(const u16x8*)&xcT[k][pxg * 8];
    float xv[8];
#pragma unroll
    for (int i = 0; i < 8; ++i) xv[i] = us2f(xu[i]);
    const float* wp = w2t + k * 64 + cg * 8;
    float wv[8];
    *(float4*)&wv[0] = *(const float4*)wp;
    *(float4*)&wv[4] = *(const float4*)(wp + 4);
#pragma unroll
    for (int i = 0; i < 8; ++i)
#pragma unroll
      for (int j = 0; j < 8; ++j) acc[i][j] = fmaf(xv[i], wv[j], acc[i][j]);
  }
#pragma unroll
  for (int i = 0; i < 8; ++i) {
    const int px = pxg * 8 + i;
    const int iy = px >> 4, ix = px & 15;
    const int py = ty * 16 + iy, pxx = tx * 16 + ix;
    const float cf = coef[py * 256 + pxx];
    const size_t g = ((size_t)((b * 256 + py) * 256 + pxx)) * 64 + cg * 8;
    const u16x8 xd = *(const u16x8*)(xio + g);
    const float4 xl0 = *(const float4*)(xlow + g);
    const float4 xl1 = *(const float4*)(xlow + g + 4);
    float xlv[8] = {xl0.x, xl0.y, xl0.z, xl0.w, xl1.x, xl1.y, xl1.z, xl1.w};
    u16x8 o;
#pragma unroll
    for (int j = 0; j < 8; ++j) {
      const float xcv = us2f(xcT[cg * 8 + j][px]);
      const float xh = gelu(acc[i][j]) + xcv;
      o[j] = f2us(cf * xlv[j] + (1.0f - cf) * xh + us2f(xd[j]));
    }
    *(u16x8*)(xio + g) = o;
  }
}

// ----------------------------------------------------------------------------
extern "C" void kernel_launch(void* const* d_in, const int* in_sizes, int n_in,
                              void* d_out, int out_size, void* d_ws, size_t ws_size,
                              hipStream_t stream) {
  const float* x_input = (const float*)d_in[0];
  const float* Wq      = (const float*)d_in[1];
  const float* Wk      = (const float*)d_in[2];
  const float* Wv      = (const float*)d_in[3];
  const float* resc    = (const float*)d_in[4];
  const float* proj_w  = (const float*)d_in[5];
  const float* proj_b  = (const float*)d_in[6];
  const float* c1a_w   = (const float*)d_in[7];
  const float* c1b_w   = (const float*)d_in[8];
  const float* c2_w    = (const float*)d_in[9];
  const float* coef    = (const float*)d_in[10];
  float* out = (float*)d_out;

  char* ws = (char*)d_ws;
  u16t* A  = (u16t*)ws;                       // 16.7M bf16
  u16t* Bb = (u16t*)(ws + 33554432);          // 16.7M bf16
  float* FT  = (float*)(ws + 67108864);
  float* IT  = FT + 65536;
  float* w1t = IT + 65536;
  float* w2t = w1t + 4096;

  k_init<<<dim3(514), dim3(256), 0, stream>>>(FT, IT, w1t, w2t, c1a_w, c2_w);
  // DCT along W: x[b,h,w,c] -> A[b,h,kw,c]
  k_transform<false, true><<<dim3(1024), dim3(256), 0, stream>>>(x_input, A, FT, 16384, 64);
  // DCT along H: A -> Bb = xdct[b,kh,kw,c]
  k_transform<true, true><<<dim3(1024), dim3(256), 0, stream>>>(A, Bb, FT, 64, 16384);
  // conv branch part 1: y1 = gelu(conv1x1(xdct)) -> A
  k_conv1<<<dim3(1024), dim3(256), 0, stream>>>(Bb, A, w1t);
  // attention branch: xdct -> x_low (parked in d_out)
  k_attn<<<dim3(1024), dim3(256), 0, stream>>>(Bb, out, Wq, Wk, Wv, resc, proj_w, proj_b);
  // dw conv + c2 + combine -> Bb (in place over xdct)
  k_conv2<<<dim3(1024), dim3(256), 0, stream>>>(A, Bb, out, w2t, c1b_w, coef);
  // IDCT along W: Bb -> A
  k_transform<true, true><<<dim3(1024), dim3(256), 0, stream>>>(Bb, A, IT, 16384, 64);
  // IDCT along H: A -> out (f32, final NHWC layout)
  k_transform<true, false><<<dim3(1024), dim3(256), 0, stream>>>(A, out, IT, 64, 16384);
}

// Round 2
// 441.085 us; speedup vs baseline: 2.0674x; 2.0674x over previous
//
#include <hip/hip_runtime.h>

#define DI __device__ __forceinline__

typedef unsigned short u16t;
typedef u16t u16x4 __attribute__((ext_vector_type(4)));
typedef u16t u16x8 __attribute__((ext_vector_type(8)));
typedef short s16x8 __attribute__((ext_vector_type(8)));   // bf16 MFMA A/B frag
typedef float f32x4 __attribute__((ext_vector_type(4)));   // MFMA C/D frag

static constexpr int PLANE = 256 * 256 * 64;   // elements per batch image
static constexpr double PI = 3.14159265358979323846264338327950288;

DI float us2f(u16t u) {
  union { unsigned int i; float f; } v; v.i = ((unsigned int)u) << 16; return v.f;
}
DI u16t f2us(float f) {            // f32 -> bf16 bits, round-to-nearest-even
  union { float f; unsigned int i; } v; v.f = f;
  unsigned int r = v.i + 0x7FFFu + ((v.i >> 16) & 1u);
  return (u16t)(r >> 16);
}
DI float gelu(float x) { return 0.5f * x * (1.0f + erff(x * 0.70710678118654752f)); }

// ------------- init: bf16 transform matrices + transposed 1x1 weights -------
// Mtf[ko][n] = 2 cos(pi (2n+1) ko / 512)          (forward, = FT[n][ko])
// Mti[ko][n] = w_n cos(pi (2ko+1) n / 512) / 256  (inverse, = IT[n][ko])
__global__ void k_init(u16t* __restrict__ Mtf, u16t* __restrict__ Mti,
                       float* __restrict__ w1t, float* __restrict__ w2t,
                       const float* __restrict__ c1a, const float* __restrict__ c2w)
{
  const int blk = blockIdx.x, t = threadIdx.x;
  if (blk < 256) {
    const int ko = blk, n = t;
    double af = PI * (2.0 * n + 1.0) * (double)ko / 512.0;
    Mtf[ko * 256 + n] = f2us((float)(2.0 * cos(af)));
    double wn = (n == 0) ? 0.5 : 1.0;
    double ai = PI * (2.0 * ko + 1.0) * (double)n / 512.0;
    Mti[ko * 256 + n] = f2us((float)(wn * cos(ai) / 256.0));
  } else if (blk == 256) {    // w1t[ci][co] = c1a[co][ci]
    for (int i = 0; i < 16; ++i) { int e = i * 256 + t; w1t[e] = c1a[(e & 63) * 64 + (e >> 6)]; }
  } else {
    for (int i = 0; i < 16; ++i) { int e = i * 256 + t; w2t[e] = c2w[(e & 63) * 64 + (e >> 6)]; }
  }
}

// ---------------- 1-D transform along one spatial axis, MFMA ----------------
// out[b, other, ko, c] = sum_n Mt[ko][n] * in[b, other, n, c]
// D[c][ko] = sum_n A[c][n] * B[n][ko];  A = XT (LDS), B = Mt rows (global/L2)
template<bool INBF, bool OUTBF>
__global__ __launch_bounds__(256) void k_tmfma(const void* __restrict__ inv,
    void* __restrict__ outv, const u16t* __restrict__ Mt,
    const int s_other, const int s_row)
{
  __shared__ __align__(16) u16t XT[64][264];   // [c][n], +8 pad
  const int t = threadIdx.x;
  const int b = blockIdx.x >> 8, other = blockIdx.x & 255;
  const size_t base = (size_t)b * PLANE + (size_t)other * (size_t)s_other;
  if constexpr (INBF) {
#pragma unroll
    for (int q = 0; q < 8; ++q) {
      const int id = q * 256 + t;               // 2048 = 256 n x 8 c-groups
      const int n = id >> 3, c8 = (id & 7) * 8;
      u16x8 u = *(const u16x8*)((const u16t*)inv + base + (size_t)n * (size_t)s_row + c8);
#pragma unroll
      for (int j = 0; j < 8; ++j) XT[c8 + j][n] = u[j];
    }
  } else {
#pragma unroll
    for (int q = 0; q < 16; ++q) {
      const int id = q * 256 + t;               // 4096 = 256 n x 16 c-groups
      const int n = id >> 4, c4 = (id & 15) * 4;
      float4 v = *(const float4*)((const float*)inv + base + (size_t)n * (size_t)s_row + c4);
      XT[c4 + 0][n] = f2us(v.x); XT[c4 + 1][n] = f2us(v.y);
      XT[c4 + 2][n] = f2us(v.z); XT[c4 + 3][n] = f2us(v.w);
    }
  }
  __syncthreads();
  const int w = t >> 6, l = t & 63;
  const int lr = l & 15, lg = l >> 4;
  f32x4 acc[4][4];                 // [c-tile][ko-tile]
#pragma unroll
  for (int i = 0; i < 4; ++i)
#pragma unroll
    for (int j = 0; j < 4; ++j) acc[i][j] = (f32x4){0.f, 0.f, 0.f, 0.f};

  // B frag: lane holds ko = w*64 + j*16 + lr, n = ks*32 + lg*8 + e
  const u16t* mrow = Mt + (size_t)(w * 64 + lr) * 256 + lg * 8;
  s16x8 bnxt[4];
#pragma unroll
  for (int j = 0; j < 4; ++j) bnxt[j] = *(const s16x8*)(mrow + j * 4096);
  for (int ks = 0; ks < 8; ++ks) {
    s16x8 bcur[4];
#pragma unroll
    for (int j = 0; j < 4; ++j) bcur[j] = bnxt[j];
    if (ks < 7) {
#pragma unroll
      for (int j = 0; j < 4; ++j) bnxt[j] = *(const s16x8*)(mrow + (ks + 1) * 32 + j * 4096);
    }
    s16x8 afr[4];                  // A frag: c = i*16 + lr, n = ks*32 + lg*8 + e
#pragma unroll
    for (int i = 0; i < 4; ++i)
      afr[i] = *(const s16x8*)&XT[i * 16 + lr][ks * 32 + lg * 8];
#pragma unroll
    for (int i = 0; i < 4; ++i)
#pragma unroll
      for (int j = 0; j < 4; ++j)
        acc[i][j] = __builtin_amdgcn_mfma_f32_16x16x32_bf16(afr[i], bcur[j], acc[i][j], 0, 0, 0);
  }
  // D: lane holds ko = w*64 + j*16 + lr;  c = i*16 + lg*4 + r (4 consecutive)
#pragma unroll
  for (int j = 0; j < 4; ++j)
#pragma unroll
    for (int i = 0; i < 4; ++i) {
      const size_t o = base + (size_t)(w * 64 + j * 16 + lr) * (size_t)s_row + i * 16 + lg * 4;
      if constexpr (OUTBF) {
        u16x4 u;
#pragma unroll
        for (int r = 0; r < 4; ++r) u[r] = f2us(acc[i][j][r]);
        *(u16x4*)((u16t*)outv + o) = u;
      } else {
        *(f32x4*)((float*)outv + o) = acc[i][j];
      }
    }
}

// ---------------- c1a: y1 = gelu(x @ w1t), pixelwise 64x64 GEMM -------------
__global__ __launch_bounds__(256) void k_conv1(const u16t* __restrict__ xin,
    u16t* __restrict__ yout, const float* __restrict__ w1t)
{
  __shared__ __align__(16) u16t xsT[64][264];   // transposed [c][px]
  const int t = threadIdx.x;
  const size_t ebase = (size_t)blockIdx.x * 16384;  // 256 px * 64 c
#pragma unroll
  for (int q = 0; q < 16; ++q) {
    const int e4 = q * 1024 + t * 4;
    const int px = e4 >> 6, c = e4 & 63;
    u16x4 u = *(const u16x4*)(xin + ebase + e4);
    xsT[c + 0][px] = u[0]; xsT[c + 1][px] = u[1];
    xsT[c + 2][px] = u[2]; xsT[c + 3][px] = u[3];
  }
  __syncthreads();
  const int pxg = t >> 3, cg = t & 7;
  float acc[8][8];
#pragma unroll
  for (int i = 0; i < 8; ++i)
#pragma unroll
    for (int j = 0; j < 8; ++j) acc[i][j] = 0.0f;
#pragma unroll 4
  for (int k = 0; k < 64; ++k) {
    u16x8 xu = *(const u16x8*)&xsT[k][pxg * 8];
    float xv[8];
#pragma unroll
    for (int i = 0; i < 8; ++i) xv[i] = us2f(xu[i]);
    const float* wp = w1t + k * 64 + cg * 8;
    float wv[8];
    *(float4*)&wv[0] = *(const float4*)wp;
    *(float4*)&wv[4] = *(const float4*)(wp + 4);
#pragma unroll
    for (int i = 0; i < 8; ++i)
#pragma unroll
      for (int j = 0; j < 8; ++j) acc[i][j] = fmaf(xv[i], wv[j], acc[i][j]);
  }
#pragma unroll
  for (int i = 0; i < 8; ++i) {
    u16x8 u;
#pragma unroll
    for (int j = 0; j < 8; ++j) u[j] = f2us(gelu(acc[i][j]));
    *(u16x8*)(yout + ebase + (size_t)(pxg * 8 + i) * 64 + cg * 8) = u;
  }
}

// ---------------- attention branch: 2 blocks (8x8) per WG -------------------
DI size_t gaddr(int nb, int mm) {
  const int b = nb >> 10, r = nb & 1023, bh = r >> 5, bw = r & 31;
  const int i = mm >> 3, j = mm & 7;
  return ((size_t)((b * 256 + bh * 8 + i) * 256 + bw * 8 + j)) * 64;
}

__global__ __launch_bounds__(256) void k_attn(const u16t* __restrict__ xdct,
    float* __restrict__ xlow, const float* __restrict__ Wq,
    const float* __restrict__ Wk, const float* __restrict__ Wv,
    const float* __restrict__ resc, const float* __restrict__ pw,
    const float* __restrict__ pb)
{
  __shared__ __align__(16) u16t XT[64][136];   // X transposed [c][px]; reused as X1T
  __shared__ __align__(16) u16t QT[64][136], KT[64][136], VT[64][136];
  __shared__ float attnS[4][16][16];           // per wave
  __shared__ float qn[2][64], kn[2][64];
  const int t = threadIdx.x;
  const int nb0 = blockIdx.x * 2;
  // stage X (2 blocks x 64 mm x 64 c), transposed
#pragma unroll
  for (int q = 0; q < 8; ++q) {
    const int e4 = q * 1024 + t * 4;
    const int px = e4 >> 6, c = e4 & 63;
    const size_t g = gaddr(nb0 + (px >> 6), px & 63) + c;
    u16x4 u = *(const u16x4*)(xdct + g);
    XT[c + 0][px] = u[0]; XT[c + 1][px] = u[1];
    XT[c + 2][px] = u[2]; XT[c + 3][px] = u[3];
  }
  __syncthreads();
  const int pxg = t >> 3, cg = t & 7;   // 32 px-groups of 4, 8 c-groups of 8

  auto gemmW = [&](const float* __restrict__ W, u16t (&DST)[64][136]) {
    float acc[4][8];
#pragma unroll
    for (int i = 0; i < 4; ++i)
#pragma unroll
      for (int j = 0; j < 8; ++j) acc[i][j] = 0.0f;
#pragma unroll 4
    for (int k = 0; k < 64; ++k) {
      u16x4 xu = *(const u16x4*)&XT[k][pxg * 4];
      float xv[4];
#pragma unroll
      for (int i = 0; i < 4; ++i) xv[i] = us2f(xu[i]);
      const float* wp = W + k * 64 + cg * 8;
      float wv[8];
      *(float4*)&wv[0] = *(const float4*)wp;
      *(float4*)&wv[4] = *(const float4*)(wp + 4);
#pragma unroll
      for (int i = 0; i < 4; ++i)
#pragma unroll
        for (int j = 0; j < 8; ++j) acc[i][j] = fmaf(xv[i], wv[j], acc[i][j]);
    }
#pragma unroll
    for (int i = 0; i < 4; ++i)
#pragma unroll
      for (int j = 0; j < 8; ++j) DST[cg * 8 + j][pxg * 4 + i] = f2us(acc[i][j]);
  };
  gemmW(Wq, QT);
  gemmW(Wk, KT);
  gemmW(Wv, VT);
  __syncthreads();
  // column L2 norms of Q and K (per block, per channel)
  {
    const int b2 = t >> 7, c = t & 63;
    if (((t >> 6) & 1) == 0) {
      float s = 0.0f;
      for (int m = 0; m < 64; ++m) { float a = us2f(QT[c][b2 * 64 + m]); s = fmaf(a, a, s); }
      qn[b2][c] = 1.0f / fmaxf(sqrtf(s), 1e-12f);
    } else {
      float s = 0.0f;
      for (int m = 0; m < 64; ++m) { float a = us2f(KT[c][b2 * 64 + m]); s = fmaf(a, a, s); }
      kn[b2][c] = 1.0f / fmaxf(sqrtf(s), 1e-12f);
    }
  }
  __syncthreads();
  // per-wave: one 8x8 block half; wave w -> block w>>1, heads (w&1)*2 + {0,1}
  const int w = t >> 6, l = t & 63;
  const int blk2 = w >> 1, mb = blk2 * 64;
  const int d = l & 15, eb = l >> 4;
  for (int hh = 0; hh < 2; ++hh) {
    const int h = (w & 1) * 2 + hh, ch = h * 16;
    float a[4] = {0.f, 0.f, 0.f, 0.f};
    for (int m = 0; m < 64; ++m) {
      float qv = us2f(QT[ch + d][mb + m]);
#pragma unroll
      for (int p = 0; p < 4; ++p)
        a[p] = fmaf(qv, us2f(KT[ch + eb * 4 + p][mb + m]), a[p]);
    }
    const float iq = qn[blk2][ch + d] * resc[h];
#pragma unroll
    for (int p = 0; p < 4; ++p) a[p] *= iq * kn[blk2][ch + eb * 4 + p];
    float mx = fmaxf(fmaxf(a[0], a[1]), fmaxf(a[2], a[3]));
    mx = fmaxf(mx, __shfl_xor(mx, 16)); mx = fmaxf(mx, __shfl_xor(mx, 32));
    float s = 0.0f;
#pragma unroll
    for (int p = 0; p < 4; ++p) { a[p] = expf(a[p] - mx); s += a[p]; }
    s += __shfl_xor(s, 16); s += __shfl_xor(s, 32);
    const float inv = 1.0f / s;
#pragma unroll
    for (int p = 0; p < 4; ++p) attnS[w][d][eb * 4 + p] = a[p] * inv;
    __syncthreads();
    // PV: lane = m; x1[m][ch+dd] = sum_e attn[dd][e] * v[e][m]
    for (int dd = 0; dd < 16; ++dd) {
      float s2 = 0.0f;
#pragma unroll
      for (int e = 0; e < 16; ++e)
        s2 = fmaf(attnS[w][dd][e], us2f(VT[ch + e][mb + l]), s2);
      XT[ch + dd][mb + l] = f2us(s2);   // X1 transposed
    }
    __syncthreads();
  }
  // proj: xlow[m][c'] = X1[m][:] @ pw + pb
  float acc[4][8];
#pragma unroll
  for (int i = 0; i < 4; ++i)
#pragma unroll
    for (int j = 0; j < 8; ++j) acc[i][j] = 0.0f;
#pragma unroll 4
  for (int k = 0; k < 64; ++k) {
    u16x4 xu = *(const u16x4*)&XT[k][pxg * 4];
    float xv[4];
#pragma unroll
    for (int i = 0; i < 4; ++i) xv[i] = us2f(xu[i]);
    const float* wp = pw + k * 64 + cg * 8;
    float wv[8];
    *(float4*)&wv[0] = *(const float4*)wp;
    *(float4*)&wv[4] = *(const float4*)(wp + 4);
#pragma unroll
    for (int i = 0; i < 4; ++i)
#pragma unroll
      for (int j = 0; j < 8; ++j) acc[i][j] = fmaf(xv[i], wv[j], acc[i][j]);
  }
  float bv[8];
  *(float4*)&bv[0] = *(const float4*)(pb + cg * 8);
  *(float4*)&bv[4] = *(const float4*)(pb + cg * 8 + 4);
#pragma unroll
  for (int i = 0; i < 4; ++i) {
    const int px = pxg * 4 + i;
    const size_t g = gaddr(nb0 + (px >> 6), px & 63) + cg * 8;
    float4 o0, o1;
    o0.x = acc[i][0] + bv[0]; o0.y = acc[i][1] + bv[1];
    o0.z = acc[i][2] + bv[2]; o0.w = acc[i][3] + bv[3];
    o1.x = acc[i][4] + bv[4]; o1.y = acc[i][5] + bv[5];
    o1.z = acc[i][6] + bv[6]; o1.w = acc[i][7] + bv[7];
    *(float4*)(xlow + g) = o0; *(float4*)(xlow + g + 4) = o1;
  }
}

// ------- depthwise 3x3 + gelu + residual + c2 GEMM + gelu + combine ---------
__global__ __launch_bounds__(256) void k_conv2(const u16t* __restrict__ y1,
    u16t* __restrict__ xio,             // xdct in, x_out (combined) out, in-place
    const float* __restrict__ xlow, const float* __restrict__ w2t,
    const float* __restrict__ dwg, const float* __restrict__ coef)
{
  __shared__ __align__(16) u16t y1h[18][18][68];
  __shared__ __align__(16) u16t xcT[64][264];
  __shared__ float dws[64][9];
  const int t = threadIdx.x;
  const int blk = blockIdx.x;
  const int b = blk >> 8, ty = (blk >> 4) & 15, tx = blk & 15;
  for (int e = t; e < 576; e += 256) dws[e / 9][e % 9] = dwg[e];
  // stage y1 tile with zero halo (16x16 interior, 18x18 staged)
  for (int s = t; s < 5184; s += 256) {
    const int r2 = s >> 4, c4 = (s & 15) * 4;
    const int iy2 = r2 / 18, ix2 = r2 % 18;
    const int py = ty * 16 + iy2 - 1, px = tx * 16 + ix2 - 1;
    u16x4 u = {0, 0, 0, 0};
    if ((unsigned)py < 256u && (unsigned)px < 256u) {
      const size_t g = ((size_t)((b * 256 + py) * 256 + px)) * 64 + c4;
      u = *(const u16x4*)(y1 + g);
    }
    y1h[iy2][ix2][c4 + 0] = u[0]; y1h[iy2][ix2][c4 + 1] = u[1];
    y1h[iy2][ix2][c4 + 2] = u[2]; y1h[iy2][ix2][c4 + 3] = u[3];
  }
  __syncthreads();
  // depthwise conv + gelu + residual -> xcT (transposed)
  {
    const int iy = t >> 4, ix = t & 15;
    const size_t gpx = ((size_t)((b * 256 + ty * 16 + iy) * 256 + tx * 16 + ix)) * 64;
    for (int c4 = 0; c4 < 64; c4 += 4) {
      float s0 = 0.f, s1 = 0.f, s2 = 0.f, s3 = 0.f;
#pragma unroll
      for (int dy = 0; dy < 3; ++dy)
#pragma unroll
        for (int dx = 0; dx < 3; ++dx) {
          const u16x4 u = *(const u16x4*)&y1h[iy + dy][ix + dx][c4];
          const int j = dy * 3 + dx;
          s0 = fmaf(us2f(u[0]), dws[c4 + 0][j], s0);
          s1 = fmaf(us2f(u[1]), dws[c4 + 1][j], s1);
          s2 = fmaf(us2f(u[2]), dws[c4 + 2][j], s2);
          s3 = fmaf(us2f(u[3]), dws[c4 + 3][j], s3);
        }
      const u16x4 x = *(const u16x4*)(xio + gpx + c4);
      xcT[c4 + 0][t] = f2us(gelu(s0) + us2f(x[0]));
      xcT[c4 + 1][t] = f2us(gelu(s1) + us2f(x[1]));
      xcT[c4 + 2][t] = f2us(gelu(s2) + us2f(x[2]));
      xcT[c4 + 3][t] = f2us(gelu(s3) + us2f(x[3]));
    }
  }
  __syncthreads();
  // c2 GEMM + gelu + residual + coef combine (+xdct), in-place into xio
  const int pxg = t >> 3, cg = t & 7;
  float acc[8][8];
#pragma unroll
  for (int i = 0; i < 8; ++i)
#pragma unroll
    for (int j = 0; j < 8; ++j) acc[i][j] = 0.0f;
#pragma unroll 4
  for (int k = 0; k < 64; ++k) {
    u16x8 xu = *(const u16x8*)&xcT[k][pxg * 8];
    float xv[8];
#pragma unroll
    for (int i = 0; i < 8; ++i) xv[i] = us2f(xu[i]);
    const float* wp = w2t + k * 64 + cg * 8;
    float wv[8];
    *(float4*)&wv[0] = *(const float4*)wp;
    *(float4*)&wv[4] = *(const float4*)(wp + 4);
#pragma unroll
    for (int i = 0; i < 8; ++i)
#pragma unroll
      for (int j = 0; j < 8; ++j) acc[i][j] = fmaf(xv[i], wv[j], acc[i][j]);
  }
#pragma unroll
  for (int i = 0; i < 8; ++i) {
    const int px = pxg * 8 + i;
    const int iy = px >> 4, ix = px & 15;
    const int py = ty * 16 + iy, pxx = tx * 16 + ix;
    const float cf = coef[py * 256 + pxx];
    const size_t g = ((size_t)((b * 256 + py) * 256 + pxx)) * 64 + cg * 8;
    const u16x8 xd = *(const u16x8*)(xio + g);
    const float4 xl0 = *(const float4*)(xlow + g);
    const float4 xl1 = *(const float4*)(xlow + g + 4);
    float xlv[8] = {xl0.x, xl0.y, xl0.z, xl0.w, xl1.x, xl1.y, xl1.z, xl1.w};
    u16x8 o;
#pragma unroll
    for (int j = 0; j < 8; ++j) {
      const float xcv = us2f(xcT[cg * 8 + j][px]);
      const float xh = gelu(acc[i][j]) + xcv;
      o[j] = f2us(cf * xlv[j] + (1.0f - cf) * xh + us2f(xd[j]));
    }
    *(u16x8*)(xio + g) = o;
  }
}

// ----------------------------------------------------------------------------
extern "C" void kernel_launch(void* const* d_in, const int* in_sizes, int n_in,
                              void* d_out, int out_size, void* d_ws, size_t ws_size,
                              hipStream_t stream) {
  const float* x_input = (const float*)d_in[0];
  const float* Wq      = (const float*)d_in[1];
  const float* Wk      = (const float*)d_in[2];
  const float* Wv      = (const float*)d_in[3];
  const float* resc    = (const float*)d_in[4];
  const float* proj_w  = (const float*)d_in[5];
  const float* proj_b  = (const float*)d_in[6];
  const float* c1a_w   = (const float*)d_in[7];
  const float* c1b_w   = (const float*)d_in[8];
  const float* c2_w    = (const float*)d_in[9];
  const float* coef    = (const float*)d_in[10];
  float* out = (float*)d_out;

  char* ws = (char*)d_ws;
  u16t* A   = (u16t*)ws;                       // 16.7M bf16
  u16t* Bb  = (u16t*)(ws + 33554432);          // 16.7M bf16
  u16t* Mtf = (u16t*)(ws + 67108864);          // 128 KB bf16
  u16t* Mti = Mtf + 65536;                     // 128 KB bf16
  float* w1t = (float*)(Mti + 65536);
  float* w2t = w1t + 4096;

  k_init<<<dim3(258), dim3(256), 0, stream>>>(Mtf, Mti, w1t, w2t, c1a_w, c2_w);
  // DCT along W: x[b,h,w,c] -> A[b,h,kw,c]
  k_tmfma<false, true><<<dim3(1024), dim3(256), 0, stream>>>(x_input, A, Mtf, 16384, 64);
  // DCT along H: A -> Bb = xdct[b,kh,kw,c]
  k_tmfma<true, true><<<dim3(1024), dim3(256), 0, stream>>>(A, Bb, Mtf, 64, 16384);
  // conv branch part 1: y1 = gelu(conv1x1(xdct)) -> A
  k_conv1<<<dim3(1024), dim3(256), 0, stream>>>(Bb, A, w1t);
  // attention branch: xdct -> x_low (parked in d_out)
  k_attn<<<dim3(2048), dim3(256), 0, stream>>>(Bb, out, Wq, Wk, Wv, resc, proj_w, proj_b);
  // dw conv + c2 + combine -> Bb (in place over xdct)
  k_conv2<<<dim3(1024), dim3(256), 0, stream>>>(A, Bb, out, w2t, c1b_w, coef);
  // IDCT along W: Bb -> A
  k_tmfma<true, true><<<dim3(1024), dim3(256), 0, stream>>>(Bb, A, Mti, 16384, 64);
  // IDCT along H: A -> out (f32, final NHWC layout)
  k_tmfma<true, false><<<dim3(1024), dim3(256), 0, stream>>>(A, out, Mti, 64, 16384);
}

// Round 3
// 334.442 us; speedup vs baseline: 2.7266x; 1.3189x over previous
//
#include <hip/hip_runtime.h>

#define DI __device__ __forceinline__

typedef unsigned short u16t;
typedef u16t u16x4 __attribute__((ext_vector_type(4)));
typedef u16t u16x8 __attribute__((ext_vector_type(8)));
typedef short s16x8 __attribute__((ext_vector_type(8)));   // bf16 MFMA A/B frag
typedef float f32x4 __attribute__((ext_vector_type(4)));   // MFMA C/D frag

static constexpr int PLANE = 256 * 256 * 64;
static constexpr double PI = 3.14159265358979323846264338327950288;

DI float us2f(u16t u) {
  union { unsigned int i; float f; } v; v.i = ((unsigned int)u) << 16; return v.f;
}
DI u16t f2us(float f) {            // f32 -> bf16, RNE
  union { float f; unsigned int i; } v; v.f = f;
  unsigned int r = v.i + 0x7FFFu + ((v.i >> 16) & 1u);
  return (u16t)(r >> 16);
}
DI float gelu(float x) { return 0.5f * x * (1.0f + erff(x * 0.70710678118654752f)); }

// ------------- init: bf16 transform matrices + bf16 weights -----------------
__global__ void k_init(u16t* __restrict__ Mtf, u16t* __restrict__ Mti,
                       u16t* __restrict__ WqT, u16t* __restrict__ WkT,
                       u16t* __restrict__ WvT, u16t* __restrict__ pwT,
                       u16t* __restrict__ W1b, u16t* __restrict__ W2b,
                       const float* __restrict__ Wq, const float* __restrict__ Wk,
                       const float* __restrict__ Wv, const float* __restrict__ pw,
                       const float* __restrict__ c1a, const float* __restrict__ c2w)
{
  const int blk = blockIdx.x, t = threadIdx.x;
  if (blk < 256) {
    const int ko = blk, n = t;
    double af = PI * (2.0 * n + 1.0) * (double)ko / 512.0;
    Mtf[ko * 256 + n] = f2us((float)(2.0 * cos(af)));
    double wn = (n == 0) ? 0.5 : 1.0;
    double ai = PI * (2.0 * ko + 1.0) * (double)n / 512.0;
    Mti[ko * 256 + n] = f2us((float)(wn * cos(ai) / 256.0));
  } else {
    for (int i = 0; i < 16; ++i) {
      const int e = i * 256 + t;
      const int d = e >> 6, c = e & 63;
      WqT[e] = f2us(Wq[c * 64 + d]);
      WkT[e] = f2us(Wk[c * 64 + d]);
      WvT[e] = f2us(Wv[c * 64 + d]);
      pwT[e] = f2us(pw[c * 64 + d]);
      W1b[e] = f2us(c1a[e]);
      W2b[e] = f2us(c2w[e]);
    }
  }
}

// ---------------- 1-D transform along one spatial axis, MFMA ----------------
template<bool INBF, bool OUTBF>
__global__ __launch_bounds__(256) void k_tmfma(const void* __restrict__ inv,
    void* __restrict__ outv, const u16t* __restrict__ Mt,
    const int s_other, const int s_row)
{
  __shared__ __align__(16) u16t XT[64][264];   // [c][n]
  const int t = threadIdx.x;
  const int b = blockIdx.x >> 8, other = blockIdx.x & 255;
  const size_t base = (size_t)b * PLANE + (size_t)other * (size_t)s_other;
  if constexpr (INBF) {
#pragma unroll
    for (int q = 0; q < 8; ++q) {
      const int id = q * 256 + t;
      const int n = id >> 3, c8 = (id & 7) * 8;
      u16x8 u = *(const u16x8*)((const u16t*)inv + base + (size_t)n * (size_t)s_row + c8);
#pragma unroll
      for (int j = 0; j < 8; ++j) XT[c8 + j][n] = u[j];
    }
  } else {
#pragma unroll
    for (int q = 0; q < 16; ++q) {
      const int id = q * 256 + t;
      const int n = id >> 4, c4 = (id & 15) * 4;
      float4 v = *(const float4*)((const float*)inv + base + (size_t)n * (size_t)s_row + c4);
      XT[c4 + 0][n] = f2us(v.x); XT[c4 + 1][n] = f2us(v.y);
      XT[c4 + 2][n] = f2us(v.z); XT[c4 + 3][n] = f2us(v.w);
    }
  }
  __syncthreads();
  const int w = t >> 6, l = t & 63;
  const int lr = l & 15, lg = l >> 4;
  f32x4 acc[4][4];
#pragma unroll
  for (int i = 0; i < 4; ++i)
#pragma unroll
    for (int j = 0; j < 4; ++j) acc[i][j] = (f32x4){0.f, 0.f, 0.f, 0.f};

  const u16t* mrow = Mt + (size_t)(w * 64 + lr) * 256 + lg * 8;
  s16x8 bnxt[4];
#pragma unroll
  for (int j = 0; j < 4; ++j) bnxt[j] = *(const s16x8*)(mrow + j * 4096);
  for (int ks = 0; ks < 8; ++ks) {
    s16x8 bcur[4];
#pragma unroll
    for (int j = 0; j < 4; ++j) bcur[j] = bnxt[j];
    if (ks < 7) {
#pragma unroll
      for (int j = 0; j < 4; ++j) bnxt[j] = *(const s16x8*)(mrow + (ks + 1) * 32 + j * 4096);
    }
    s16x8 afr[4];
#pragma unroll
    for (int i = 0; i < 4; ++i)
      afr[i] = *(const s16x8*)&XT[i * 16 + lr][ks * 32 + lg * 8];
#pragma unroll
    for (int i = 0; i < 4; ++i)
#pragma unroll
      for (int j = 0; j < 4; ++j)
        acc[i][j] = __builtin_amdgcn_mfma_f32_16x16x32_bf16(afr[i], bcur[j], acc[i][j], 0, 0, 0);
  }
#pragma unroll
  for (int j = 0; j < 4; ++j)
#pragma unroll
    for (int i = 0; i < 4; ++i) {
      const size_t o = base + (size_t)(w * 64 + j * 16 + lr) * (size_t)s_row + i * 16 + lg * 4;
      if constexpr (OUTBF) {
        u16x4 u;
#pragma unroll
        for (int r = 0; r < 4; ++r) u[r] = f2us(acc[i][j][r]);
        *(u16x4*)((u16t*)outv + o) = u;
      } else {
        *(f32x4*)((float*)outv + o) = acc[i][j];
      }
    }
}

// -------- c1a: y1 = gelu(x @ W1), MFMA, zero LDS (B-frags from global) ------
__global__ __launch_bounds__(256, 4) void k_conv1(const u16t* __restrict__ xin,
    u16t* __restrict__ yout, const u16t* __restrict__ W1b)
{
  const int t = threadIdx.x, w = t >> 6, l = t & 63;
  const int lr = l & 15, lg = l >> 4;
  const size_t ebase = (size_t)blockIdx.x * 16384;  // 256 px * 64 c
  s16x8 af[4][2];                        // A = W1b[co][ci]
#pragma unroll
  for (int mt = 0; mt < 4; ++mt)
#pragma unroll
    for (int ks = 0; ks < 2; ++ks)
      af[mt][ks] = *(const s16x8*)(W1b + (mt * 16 + lr) * 64 + ks * 32 + lg * 8);
  f32x4 acc[4][4];
#pragma unroll
  for (int i = 0; i < 4; ++i)
#pragma unroll
    for (int j = 0; j < 4; ++j) acc[i][j] = (f32x4){0.f, 0.f, 0.f, 0.f};
#pragma unroll
  for (int nt = 0; nt < 4; ++nt) {
    const int px = w * 64 + nt * 16 + lr;
#pragma unroll
    for (int ks = 0; ks < 2; ++ks) {
      s16x8 bf = *(const s16x8*)(xin + ebase + (size_t)px * 64 + ks * 32 + lg * 8);
#pragma unroll
      for (int mt = 0; mt < 4; ++mt)
        acc[mt][nt] = __builtin_amdgcn_mfma_f32_16x16x32_bf16(af[mt][ks], bf, acc[mt][nt], 0, 0, 0);
    }
  }
#pragma unroll
  for (int mt = 0; mt < 4; ++mt)
#pragma unroll
    for (int nt = 0; nt < 4; ++nt) {
      const int px = w * 64 + nt * 16 + lr;
      u16x4 u;
#pragma unroll
      for (int r = 0; r < 4; ++r) u[r] = f2us(gelu(acc[mt][nt][r]));
      *(u16x4*)(yout + ebase + (size_t)px * 64 + mt * 16 + lg * 4) = u;
    }
}

// ---------------- attention branch: 1 block per WG, MFMA --------------------
DI size_t gaddr(int nb, int mm) {
  const int b = nb >> 10, r = nb & 1023, bh = r >> 5, bw = r & 31;
  const int i = mm >> 3, j = mm & 7;
  return ((size_t)((b * 256 + bh * 8 + i) * 256 + bw * 8 + j)) * 64;
}

__global__ __launch_bounds__(256, 3) void k_attn(const u16t* __restrict__ xdct,
    u16t* __restrict__ xlow, const u16t* __restrict__ WqT,
    const u16t* __restrict__ WkT, const u16t* __restrict__ WvT,
    const u16t* __restrict__ pwT, const float* __restrict__ resc,
    const float* __restrict__ pb)
{
  __shared__ __align__(16) u16t Xs[64][72], QT[64][72], KT[64][72], VT[64][72], X1[64][72];
  __shared__ __align__(16) u16t PSb[4][16][24];
  const int t = threadIdx.x, w = t >> 6, l = t & 63;
  const int lr = l & 15, lg = l >> 4;
  const int nb = blockIdx.x;
  // stage X [m][c]
#pragma unroll
  for (int q = 0; q < 2; ++q) {
    const int id = q * 256 + t, px = id >> 3, c8 = (id & 7) * 8;
    *(u16x8*)&Xs[px][c8] = *(const u16x8*)(xdct + gaddr(nb, px) + c8);
  }
  __syncthreads();
  // A-frags of X (row=m, k=c) — shared by Q,K,V GEMMs
  s16x8 afr[4][2];
#pragma unroll
  for (int mt = 0; mt < 4; ++mt)
#pragma unroll
    for (int ks = 0; ks < 2; ++ks)
      afr[mt][ks] = *(const s16x8*)&Xs[mt * 16 + lr][ks * 32 + lg * 8];

  // QKV: D[m][d], wave w owns d-tile w (= head w). Store transposed to DST[d][m].
  auto qkv = [&](const u16t* __restrict__ WT, u16t (&DST)[64][72], bool donorm) {
    f32x4 acc[4];
#pragma unroll
    for (int mt = 0; mt < 4; ++mt) acc[mt] = (f32x4){0.f, 0.f, 0.f, 0.f};
#pragma unroll
    for (int ks = 0; ks < 2; ++ks) {
      s16x8 bf = *(const s16x8*)(WT + (w * 16 + lr) * 64 + ks * 32 + lg * 8);
#pragma unroll
      for (int mt = 0; mt < 4; ++mt)
        acc[mt] = __builtin_amdgcn_mfma_f32_16x16x32_bf16(afr[mt][ks], bf, acc[mt], 0, 0, 0);
    }
    float inv = 1.0f;
    if (donorm) {     // L2 norm over all 64 m for this lane's d
      float ss = 0.f;
#pragma unroll
      for (int mt = 0; mt < 4; ++mt)
#pragma unroll
        for (int r = 0; r < 4; ++r) ss = fmaf(acc[mt][r], acc[mt][r], ss);
      ss += __shfl_xor(ss, 16); ss += __shfl_xor(ss, 32);
      inv = 1.0f / fmaxf(sqrtf(ss), 1e-12f);
    }
#pragma unroll
    for (int mt = 0; mt < 4; ++mt) {
      u16x4 u;
#pragma unroll
      for (int r = 0; r < 4; ++r) u[r] = f2us(acc[mt][r] * inv);
      *(u16x4*)&DST[w * 16 + lr][mt * 16 + lg * 4] = u;
    }
  };
  qkv(WqT, QT, true);
  qkv(WkT, KT, true);
  qkv(WvT, VT, false);

  // S^T[e][d] = sum_m k[e][m] q[d][m]  (A=K rows, B=Q cols), head = w
  f32x4 s = (f32x4){0.f, 0.f, 0.f, 0.f};
#pragma unroll
  for (int ks = 0; ks < 2; ++ks) {
    s16x8 ak = *(const s16x8*)&KT[w * 16 + lr][ks * 32 + lg * 8];
    s16x8 bq = *(const s16x8*)&QT[w * 16 + lr][ks * 32 + lg * 8];
    s = __builtin_amdgcn_mfma_f32_16x16x32_bf16(ak, bq, s, 0, 0, 0);
  }
  const float rs = resc[w];
  float a[4];
#pragma unroll
  for (int r = 0; r < 4; ++r) a[r] = s[r] * rs;
  // softmax over e (rows of S^T = regs + lg groups)
  float mx = fmaxf(fmaxf(a[0], a[1]), fmaxf(a[2], a[3]));
  mx = fmaxf(mx, __shfl_xor(mx, 16)); mx = fmaxf(mx, __shfl_xor(mx, 32));
  float sm = 0.f;
#pragma unroll
  for (int r = 0; r < 4; ++r) { a[r] = expf(a[r] - mx); sm += a[r]; }
  sm += __shfl_xor(sm, 16); sm += __shfl_xor(sm, 32);
  const float sinv = 1.0f / sm;
  u16x4 pp;
#pragma unroll
  for (int r = 0; r < 4; ++r) pp[r] = f2us(a[r] * sinv);
  *(u16x4*)&PSb[w][lr][lg * 4] = pp;     // P[d=lr][e=lg*4+r]

  // PV: D[dd][m] = sum_e P[dd][e] v[e][m]   (K=32, e>=16 zero via frags)
  const s16x8 zf = (s16x8){0, 0, 0, 0, 0, 0, 0, 0};
  s16x8 pa = zf;
  if (lg < 2) pa = *(const s16x8*)&PSb[w][lr][lg * 8];
#pragma unroll
  for (int mt = 0; mt < 4; ++mt) {
    s16x8 bv = zf;
    if (lg < 2) {
#pragma unroll
      for (int j = 0; j < 8; ++j) bv[j] = (short)VT[w * 16 + lg * 8 + j][mt * 16 + lr];
    }
    f32x4 o = __builtin_amdgcn_mfma_f32_16x16x32_bf16(pa, bv, (f32x4){0.f, 0.f, 0.f, 0.f}, 0, 0, 0);
    u16x4 u;
#pragma unroll
    for (int r = 0; r < 4; ++r) u[r] = f2us(o[r]);
    *(u16x4*)&X1[mt * 16 + lr][w * 16 + lg * 4] = u;   // X1[m][ch+dd]
  }
  __syncthreads();

  // proj: D[c'][m] = sum_c pwT[c'][c] X1[m][c];  wave w owns m-tile w
  f32x4 pacc[4];
#pragma unroll
  for (int mt = 0; mt < 4; ++mt) pacc[mt] = (f32x4){0.f, 0.f, 0.f, 0.f};
#pragma unroll
  for (int ks = 0; ks < 2; ++ks) {
    s16x8 bx = *(const s16x8*)&X1[w * 16 + lr][ks * 32 + lg * 8];
#pragma unroll
    for (int mt = 0; mt < 4; ++mt) {
      s16x8 ap = *(const s16x8*)(pwT + (mt * 16 + lr) * 64 + ks * 32 + lg * 8);
      pacc[mt] = __builtin_amdgcn_mfma_f32_16x16x32_bf16(ap, bx, pacc[mt], 0, 0, 0);
    }
  }
  const size_t gm = gaddr(nb, w * 16 + lr);
#pragma unroll
  for (int mt = 0; mt < 4; ++mt) {
    const float4 bias = *(const float4*)(pb + mt * 16 + lg * 4);
    u16x4 u;
    u[0] = f2us(pacc[mt][0] + bias.x); u[1] = f2us(pacc[mt][1] + bias.y);
    u[2] = f2us(pacc[mt][2] + bias.z); u[3] = f2us(pacc[mt][3] + bias.w);
    *(u16x4*)(xlow + gm + mt * 16 + lg * 4) = u;
  }
}

// ------- depthwise 3x3 + gelu + residual + c2 MFMA GEMM + combine -----------
__global__ __launch_bounds__(256, 3) void k_conv2(const u16t* __restrict__ y1,
    u16t* __restrict__ xio, const u16t* __restrict__ xlow,
    const u16t* __restrict__ W2b, const float* __restrict__ dwg,
    const float* __restrict__ coef)
{
  __shared__ __align__(16) char smem[44064];     // y1h[18][18][68] U xc[256][72]
  __shared__ float dws[64][9];
  u16t (*y1h)[18][68] = (u16t(*)[18][68])smem;
  u16t (*xc)[72]      = (u16t(*)[72])smem;
  const int t = threadIdx.x;
  const int blk = blockIdx.x;
  const int b = blk >> 8, ty = (blk >> 4) & 15, tx = blk & 15;
  for (int e = t; e < 576; e += 256) dws[e / 9][e % 9] = dwg[e];
  // stage y1 tile with zero halo
  for (int s = t; s < 5184; s += 256) {
    const int r2 = s >> 4, c4 = (s & 15) * 4;
    const int iy2 = r2 / 18, ix2 = r2 % 18;
    const int py = ty * 16 + iy2 - 1, px = tx * 16 + ix2 - 1;
    u16x4 u = {0, 0, 0, 0};
    if ((unsigned)py < 256u && (unsigned)px < 256u) {
      const size_t g = ((size_t)((b * 256 + py) * 256 + px)) * 64 + c4;
      u = *(const u16x4*)(y1 + g);
    }
    y1h[iy2][ix2][c4 + 0] = u[0]; y1h[iy2][ix2][c4 + 1] = u[1];
    y1h[iy2][ix2][c4 + 2] = u[2]; y1h[iy2][ix2][c4 + 3] = u[3];
  }
  __syncthreads();
  // depthwise conv + gelu + residual -> bf16 regs
  u16x4 xcr[16];
  {
    const int iy = t >> 4, ix = t & 15;
    const size_t gpx = ((size_t)((b * 256 + ty * 16 + iy) * 256 + tx * 16 + ix)) * 64;
#pragma unroll
    for (int c4i = 0; c4i < 16; ++c4i) {
      const int c4 = c4i * 4;
      float s0 = 0.f, s1 = 0.f, s2 = 0.f, s3 = 0.f;
#pragma unroll
      for (int dy = 0; dy < 3; ++dy)
#pragma unroll
        for (int dx = 0; dx < 3; ++dx) {
          const u16x4 u = *(const u16x4*)&y1h[iy + dy][ix + dx][c4];
          const int j = dy * 3 + dx;
          s0 = fmaf(us2f(u[0]), dws[c4 + 0][j], s0);
          s1 = fmaf(us2f(u[1]), dws[c4 + 1][j], s1);
          s2 = fmaf(us2f(u[2]), dws[c4 + 2][j], s2);
          s3 = fmaf(us2f(u[3]), dws[c4 + 3][j], s3);
        }
      const u16x4 x = *(const u16x4*)(xio + gpx + c4);
      u16x4 o;
      o[0] = f2us(gelu(s0) + us2f(x[0])); o[1] = f2us(gelu(s1) + us2f(x[1]));
      o[2] = f2us(gelu(s2) + us2f(x[2])); o[3] = f2us(gelu(s3) + us2f(x[3]));
      xcr[c4i] = o;
    }
  }
  __syncthreads();          // all y1h reads done -> safe to overwrite
#pragma unroll
  for (int i = 0; i < 16; ++i) *(u16x4*)&xc[t][i * 4] = xcr[i];
  __syncthreads();
  // c2 GEMM: D[c'][px];  A = W2b (global), B = xc (LDS)
  const int w = t >> 6, l = t & 63;
  const int lr = l & 15, lg = l >> 4;
  s16x8 af[4][2];
#pragma unroll
  for (int mt = 0; mt < 4; ++mt)
#pragma unroll
    for (int ks = 0; ks < 2; ++ks)
      af[mt][ks] = *(const s16x8*)(W2b + (mt * 16 + lr) * 64 + ks * 32 + lg * 8);
  f32x4 acc[4][4];
#pragma unroll
  for (int i = 0; i < 4; ++i)
#pragma unroll
    for (int j = 0; j < 4; ++j) acc[i][j] = (f32x4){0.f, 0.f, 0.f, 0.f};
#pragma unroll
  for (int nt = 0; nt < 4; ++nt) {
    const int p = w * 64 + nt * 16 + lr;
#pragma unroll
    for (int ks = 0; ks < 2; ++ks) {
      s16x8 bf = *(const s16x8*)&xc[p][ks * 32 + lg * 8];
#pragma unroll
      for (int mt = 0; mt < 4; ++mt)
        acc[mt][nt] = __builtin_amdgcn_mfma_f32_16x16x32_bf16(af[mt][ks], bf, acc[mt][nt], 0, 0, 0);
    }
  }
  // epilogue: gelu + residual(xc) + coef combine (+xdct) -> xio
#pragma unroll
  for (int nt = 0; nt < 4; ++nt) {
    const int p = w * 64 + nt * 16 + lr;
    const int iy = p >> 4, ix = p & 15;
    const int py = ty * 16 + iy, pxx = tx * 16 + ix;
    const float cf = coef[py * 256 + pxx];
    const size_t gb = ((size_t)((b * 256 + py) * 256 + pxx)) * 64;
#pragma unroll
    for (int mt = 0; mt < 4; ++mt) {
      const int c0 = mt * 16 + lg * 4;
      const u16x4 xd = *(const u16x4*)(xio + gb + c0);
      const u16x4 xl = *(const u16x4*)(xlow + gb + c0);
      const u16x4 xr = *(const u16x4*)&xc[p][c0];
      u16x4 o;
#pragma unroll
      for (int r = 0; r < 4; ++r) {
        const float xh = gelu(acc[mt][nt][r]) + us2f(xr[r]);
        o[r] = f2us(cf * us2f(xl[r]) + (1.0f - cf) * xh + us2f(xd[r]));
      }
      *(u16x4*)(xio + gb + c0) = o;
    }
  }
}

// ----------------------------------------------------------------------------
extern "C" void kernel_launch(void* const* d_in, const int* in_sizes, int n_in,
                              void* d_out, int out_size, void* d_ws, size_t ws_size,
                              hipStream_t stream) {
  const float* x_input = (const float*)d_in[0];
  const float* Wq      = (const float*)d_in[1];
  const float* Wk      = (const float*)d_in[2];
  const float* Wv      = (const float*)d_in[3];
  const float* resc    = (const float*)d_in[4];
  const float* proj_w  = (const float*)d_in[5];
  const float* proj_b  = (const float*)d_in[6];
  const float* c1a_w   = (const float*)d_in[7];
  const float* c1b_w   = (const float*)d_in[8];
  const float* c2_w    = (const float*)d_in[9];
  const float* coef    = (const float*)d_in[10];
  float* out = (float*)d_out;

  char* ws = (char*)d_ws;
  u16t* A   = (u16t*)ws;                       // 33.5 MB
  u16t* Bb  = (u16t*)(ws + 33554432);          // 33.5 MB
  u16t* Mtf = (u16t*)(ws + 67108864);
  u16t* Mti = Mtf + 65536;
  u16t* WqT = Mti + 65536;
  u16t* WkT = WqT + 4096;
  u16t* WvT = WkT + 4096;
  u16t* pwT = WvT + 4096;
  u16t* W1b = pwT + 4096;
  u16t* W2b = W1b + 4096;
  u16t* xlow = (u16t*)d_out;                   // bf16 scratch, overwritten later

  k_init<<<dim3(257), dim3(256), 0, stream>>>(Mtf, Mti, WqT, WkT, WvT, pwT, W1b, W2b,
                                              Wq, Wk, Wv, proj_w, c1a_w, c2_w);
  // DCT along W: x -> A
  k_tmfma<false, true><<<dim3(1024), dim3(256), 0, stream>>>(x_input, A, Mtf, 16384, 64);
  // DCT along H: A -> Bb (= xdct)
  k_tmfma<true, true><<<dim3(1024), dim3(256), 0, stream>>>(A, Bb, Mtf, 64, 16384);
  // conv branch part 1: y1 = gelu(conv1x1(xdct)) -> A
  k_conv1<<<dim3(1024), dim3(256), 0, stream>>>(Bb, A, W1b);
  // attention branch: xdct -> x_low (bf16, parked in d_out)
  k_attn<<<dim3(4096), dim3(256), 0, stream>>>(Bb, xlow, WqT, WkT, WvT, pwT, resc, proj_b);
  // dw conv + c2 + combine -> Bb (in place over xdct)
  k_conv2<<<dim3(1024), dim3(256), 0, stream>>>(A, Bb, xlow, W2b, c1b_w, coef);
  // IDCT along W: Bb -> A
  k_tmfma<true, true><<<dim3(1024), dim3(256), 0, stream>>>(Bb, A, Mti, 16384, 64);
  // IDCT along H: A -> out (f32, final NHWC)
  k_tmfma<true, false><<<dim3(1024), dim3(256), 0, stream>>>(A, out, Mti, 64, 16384);
}

// Round 4
// 324.328 us; speedup vs baseline: 2.8117x; 1.0312x over previous
//
#include <hip/hip_runtime.h>

#define DI __device__ __forceinline__

typedef unsigned short u16t;
typedef u16t u16x4 __attribute__((ext_vector_type(4)));
typedef u16t u16x8 __attribute__((ext_vector_type(8)));
typedef short s16x8 __attribute__((ext_vector_type(8)));   // bf16 MFMA A/B frag
typedef float f32x4 __attribute__((ext_vector_type(4)));   // MFMA C/D frag

static constexpr int PLANE = 256 * 256 * 64;
static constexpr double PI = 3.14159265358979323846264338327950288;

DI float us2f(u16t u) {
  union { unsigned int i; float f; } v; v.i = ((unsigned int)u) << 16; return v.f;
}
DI u16t f2us(float f) {            // f32 -> bf16, RNE
  union { float f; unsigned int i; } v; v.f = f;
  unsigned int r = v.i + 0x7FFFu + ((v.i >> 16) & 1u);
  return (u16t)(r >> 16);
}
DI float gelu(float x) { return 0.5f * x * (1.0f + erff(x * 0.70710678118654752f)); }

// ------------- init: bf16 transform matrices + bf16 weights -----------------
__global__ void k_init(u16t* __restrict__ Mtf, u16t* __restrict__ Mti,
                       u16t* __restrict__ WqT, u16t* __restrict__ WkT,
                       u16t* __restrict__ WvT, u16t* __restrict__ pwT,
                       u16t* __restrict__ W1b, u16t* __restrict__ W2b,
                       const float* __restrict__ Wq, const float* __restrict__ Wk,
                       const float* __restrict__ Wv, const float* __restrict__ pw,
                       const float* __restrict__ c1a, const float* __restrict__ c2w)
{
  const int blk = blockIdx.x, t = threadIdx.x;
  if (blk < 256) {
    const int ko = blk, n = t;
    double af = PI * (2.0 * n + 1.0) * (double)ko / 512.0;
    Mtf[ko * 256 + n] = f2us((float)(2.0 * cos(af)));
    double wn = (n == 0) ? 0.5 : 1.0;
    double ai = PI * (2.0 * ko + 1.0) * (double)n / 512.0;
    Mti[ko * 256 + n] = f2us((float)(wn * cos(ai) / 256.0));
  } else {
    for (int i = 0; i < 16; ++i) {
      const int e = i * 256 + t;
      const int d = e >> 6, c = e & 63;
      WqT[e] = f2us(Wq[c * 64 + d]);
      WkT[e] = f2us(Wk[c * 64 + d]);
      WvT[e] = f2us(Wv[c * 64 + d]);
      pwT[e] = f2us(pw[c * 64 + d]);
      W1b[e] = f2us(c1a[e]);
      W2b[e] = f2us(c2w[e]);
    }
  }
}

// ---------------- 1-D transform along one spatial axis, MFMA ----------------
template<bool INBF, bool OUTBF>
__global__ __launch_bounds__(256) void k_tmfma(const void* __restrict__ inv,
    void* __restrict__ outv, const u16t* __restrict__ Mt,
    const int s_other, const int s_row)
{
  __shared__ __align__(16) u16t XT[64][264];   // [c][n]
  const int t = threadIdx.x;
  const int b = blockIdx.x >> 8, other = blockIdx.x & 255;
  const size_t base = (size_t)b * PLANE + (size_t)other * (size_t)s_other;
  if constexpr (INBF) {
#pragma unroll
    for (int q = 0; q < 8; ++q) {
      const int id = q * 256 + t;
      const int n = id >> 3, c8 = (id & 7) * 8;
      u16x8 u = *(const u16x8*)((const u16t*)inv + base + (size_t)n * (size_t)s_row + c8);
#pragma unroll
      for (int j = 0; j < 8; ++j) XT[c8 + j][n] = u[j];
    }
  } else {
#pragma unroll
    for (int q = 0; q < 16; ++q) {
      const int id = q * 256 + t;
      const int n = id >> 4, c4 = (id & 15) * 4;
      float4 v = *(const float4*)((const float*)inv + base + (size_t)n * (size_t)s_row + c4);
      XT[c4 + 0][n] = f2us(v.x); XT[c4 + 1][n] = f2us(v.y);
      XT[c4 + 2][n] = f2us(v.z); XT[c4 + 3][n] = f2us(v.w);
    }
  }
  __syncthreads();
  const int w = t >> 6, l = t & 63;
  const int lr = l & 15, lg = l >> 4;
  f32x4 acc[4][4];
#pragma unroll
  for (int i = 0; i < 4; ++i)
#pragma unroll
    for (int j = 0; j < 4; ++j) acc[i][j] = (f32x4){0.f, 0.f, 0.f, 0.f};

  const u16t* mrow = Mt + (size_t)(w * 64 + lr) * 256 + lg * 8;
  s16x8 bnxt[4];
#pragma unroll
  for (int j = 0; j < 4; ++j) bnxt[j] = *(const s16x8*)(mrow + j * 4096);
  for (int ks = 0; ks < 8; ++ks) {
    s16x8 bcur[4];
#pragma unroll
    for (int j = 0; j < 4; ++j) bcur[j] = bnxt[j];
    if (ks < 7) {
#pragma unroll
      for (int j = 0; j < 4; ++j) bnxt[j] = *(const s16x8*)(mrow + (ks + 1) * 32 + j * 4096);
    }
    s16x8 afr[4];
#pragma unroll
    for (int i = 0; i < 4; ++i)
      afr[i] = *(const s16x8*)&XT[i * 16 + lr][ks * 32 + lg * 8];
#pragma unroll
    for (int i = 0; i < 4; ++i)
#pragma unroll
      for (int j = 0; j < 4; ++j)
        acc[i][j] = __builtin_amdgcn_mfma_f32_16x16x32_bf16(afr[i], bcur[j], acc[i][j], 0, 0, 0);
  }
#pragma unroll
  for (int j = 0; j < 4; ++j)
#pragma unroll
    for (int i = 0; i < 4; ++i) {
      const size_t o = base + (size_t)(w * 64 + j * 16 + lr) * (size_t)s_row + i * 16 + lg * 4;
      if constexpr (OUTBF) {
        u16x4 u;
#pragma unroll
        for (int r = 0; r < 4; ++r) u[r] = f2us(acc[i][j][r]);
        *(u16x4*)((u16t*)outv + o) = u;
      } else {
        *(f32x4*)((float*)outv + o) = acc[i][j];
      }
    }
}

// -------- c1a: y1 = gelu(x @ W1), MFMA, zero LDS (B-frags from global) ------
__global__ __launch_bounds__(256, 4) void k_conv1(const u16t* __restrict__ xin,
    u16t* __restrict__ yout, const u16t* __restrict__ W1b)
{
  const int t = threadIdx.x, w = t >> 6, l = t & 63;
  const int lr = l & 15, lg = l >> 4;
  const size_t ebase = (size_t)blockIdx.x * 16384;  // 256 px * 64 c
  s16x8 af[4][2];                        // A = W1b[co][ci]
#pragma unroll
  for (int mt = 0; mt < 4; ++mt)
#pragma unroll
    for (int ks = 0; ks < 2; ++ks)
      af[mt][ks] = *(const s16x8*)(W1b + (mt * 16 + lr) * 64 + ks * 32 + lg * 8);
  f32x4 acc[4][4];
#pragma unroll
  for (int i = 0; i < 4; ++i)
#pragma unroll
    for (int j = 0; j < 4; ++j) acc[i][j] = (f32x4){0.f, 0.f, 0.f, 0.f};
#pragma unroll
  for (int nt = 0; nt < 4; ++nt) {
    const int px = w * 64 + nt * 16 + lr;
#pragma unroll
    for (int ks = 0; ks < 2; ++ks) {
      s16x8 bf = *(const s16x8*)(xin + ebase + (size_t)px * 64 + ks * 32 + lg * 8);
#pragma unroll
      for (int mt = 0; mt < 4; ++mt)
        acc[mt][nt] = __builtin_amdgcn_mfma_f32_16x16x32_bf16(af[mt][ks], bf, acc[mt][nt], 0, 0, 0);
    }
  }
#pragma unroll
  for (int mt = 0; mt < 4; ++mt)
#pragma unroll
    for (int nt = 0; nt < 4; ++nt) {
      const int px = w * 64 + nt * 16 + lr;
      u16x4 u;
#pragma unroll
      for (int r = 0; r < 4; ++r) u[r] = f2us(gelu(acc[mt][nt][r]));
      *(u16x4*)(yout + ebase + (size_t)px * 64 + mt * 16 + lg * 4) = u;
    }
}

// ---------------- attention branch: 1 block per WG, MFMA --------------------
DI size_t gaddr(int nb, int mm) {
  const int b = nb >> 10, r = nb & 1023, bh = r >> 5, bw = r & 31;
  const int i = mm >> 3, j = mm & 7;
  return ((size_t)((b * 256 + bh * 8 + i) * 256 + bw * 8 + j)) * 64;
}

__global__ __launch_bounds__(256, 3) void k_attn(const u16t* __restrict__ xdct,
    u16t* __restrict__ xlow, const u16t* __restrict__ WqT,
    const u16t* __restrict__ WkT, const u16t* __restrict__ WvT,
    const u16t* __restrict__ pwT, const float* __restrict__ resc,
    const float* __restrict__ pb)
{
  __shared__ __align__(16) u16t Xs[64][72], QT[64][72], KT[64][72], VT[64][72], X1[64][72];
  __shared__ __align__(16) u16t PSb[4][16][24];
  const int t = threadIdx.x, w = t >> 6, l = t & 63;
  const int lr = l & 15, lg = l >> 4;
  const int nb = blockIdx.x;
  // stage X [m][c]
#pragma unroll
  for (int q = 0; q < 2; ++q) {
    const int id = q * 256 + t, px = id >> 3, c8 = (id & 7) * 8;
    *(u16x8*)&Xs[px][c8] = *(const u16x8*)(xdct + gaddr(nb, px) + c8);
  }
  __syncthreads();
  // A-frags of X (row=m, k=c) — shared by Q,K,V GEMMs
  s16x8 afr[4][2];
#pragma unroll
  for (int mt = 0; mt < 4; ++mt)
#pragma unroll
    for (int ks = 0; ks < 2; ++ks)
      afr[mt][ks] = *(const s16x8*)&Xs[mt * 16 + lr][ks * 32 + lg * 8];

  // QKV: D[m][d], wave w owns d-tile w (= head w). Store transposed to DST[d][m].
  auto qkv = [&](const u16t* __restrict__ WT, u16t (&DST)[64][72], bool donorm) {
    f32x4 acc[4];
#pragma unroll
    for (int mt = 0; mt < 4; ++mt) acc[mt] = (f32x4){0.f, 0.f, 0.f, 0.f};
#pragma unroll
    for (int ks = 0; ks < 2; ++ks) {
      s16x8 bf = *(const s16x8*)(WT + (w * 16 + lr) * 64 + ks * 32 + lg * 8);
#pragma unroll
      for (int mt = 0; mt < 4; ++mt)
        acc[mt] = __builtin_amdgcn_mfma_f32_16x16x32_bf16(afr[mt][ks], bf, acc[mt], 0, 0, 0);
    }
    float inv = 1.0f;
    if (donorm) {     // L2 norm over all 64 m for this lane's d
      float ss = 0.f;
#pragma unroll
      for (int mt = 0; mt < 4; ++mt)
#pragma unroll
        for (int r = 0; r < 4; ++r) ss = fmaf(acc[mt][r], acc[mt][r], ss);
      ss += __shfl_xor(ss, 16); ss += __shfl_xor(ss, 32);
      inv = 1.0f / fmaxf(sqrtf(ss), 1e-12f);
    }
#pragma unroll
    for (int mt = 0; mt < 4; ++mt) {
      u16x4 u;
#pragma unroll
      for (int r = 0; r < 4; ++r) u[r] = f2us(acc[mt][r] * inv);
      *(u16x4*)&DST[w * 16 + lr][mt * 16 + lg * 4] = u;
    }
  };
  qkv(WqT, QT, true);
  qkv(WkT, KT, true);
  qkv(WvT, VT, false);

  // S^T[e][d] = sum_m k[e][m] q[d][m]  (A=K rows, B=Q cols), head = w
  f32x4 s = (f32x4){0.f, 0.f, 0.f, 0.f};
#pragma unroll
  for (int ks = 0; ks < 2; ++ks) {
    s16x8 ak = *(const s16x8*)&KT[w * 16 + lr][ks * 32 + lg * 8];
    s16x8 bq = *(const s16x8*)&QT[w * 16 + lr][ks * 32 + lg * 8];
    s = __builtin_amdgcn_mfma_f32_16x16x32_bf16(ak, bq, s, 0, 0, 0);
  }
  const float rs = resc[w];
  float a[4];
#pragma unroll
  for (int r = 0; r < 4; ++r) a[r] = s[r] * rs;
  // softmax over e (rows of S^T = regs + lg groups)
  float mx = fmaxf(fmaxf(a[0], a[1]), fmaxf(a[2], a[3]));
  mx = fmaxf(mx, __shfl_xor(mx, 16)); mx = fmaxf(mx, __shfl_xor(mx, 32));
  float sm = 0.f;
#pragma unroll
  for (int r = 0; r < 4; ++r) { a[r] = expf(a[r] - mx); sm += a[r]; }
  sm += __shfl_xor(sm, 16); sm += __shfl_xor(sm, 32);
  const float sinv = 1.0f / sm;
  u16x4 pp;
#pragma unroll
  for (int r = 0; r < 4; ++r) pp[r] = f2us(a[r] * sinv);
  *(u16x4*)&PSb[w][lr][lg * 4] = pp;     // P[d=lr][e=lg*4+r]

  // PV: D[dd][m] = sum_e P[dd][e] v[e][m]   (K=32, e>=16 zero via frags)
  const s16x8 zf = (s16x8){0, 0, 0, 0, 0, 0, 0, 0};
  s16x8 pa = zf;
  if (lg < 2) pa = *(const s16x8*)&PSb[w][lr][lg * 8];
#pragma unroll
  for (int mt = 0; mt < 4; ++mt) {
    s16x8 bv = zf;
    if (lg < 2) {
#pragma unroll
      for (int j = 0; j < 8; ++j) bv[j] = (short)VT[w * 16 + lg * 8 + j][mt * 16 + lr];
    }
    f32x4 o = __builtin_amdgcn_mfma_f32_16x16x32_bf16(pa, bv, (f32x4){0.f, 0.f, 0.f, 0.f}, 0, 0, 0);
    u16x4 u;
#pragma unroll
    for (int r = 0; r < 4; ++r) u[r] = f2us(o[r]);
    *(u16x4*)&X1[mt * 16 + lr][w * 16 + lg * 4] = u;   // X1[m][ch+dd]
  }
  __syncthreads();

  // proj: D[c'][m] = sum_c pwT[c'][c] X1[m][c];  wave w owns m-tile w
  f32x4 pacc[4];
#pragma unroll
  for (int mt = 0; mt < 4; ++mt) pacc[mt] = (f32x4){0.f, 0.f, 0.f, 0.f};
#pragma unroll
  for (int ks = 0; ks < 2; ++ks) {
    s16x8 bx = *(const s16x8*)&X1[w * 16 + lr][ks * 32 + lg * 8];
#pragma unroll
    for (int mt = 0; mt < 4; ++mt) {
      s16x8 ap = *(const s16x8*)(pwT + (mt * 16 + lr) * 64 + ks * 32 + lg * 8);
      pacc[mt] = __builtin_amdgcn_mfma_f32_16x16x32_bf16(ap, bx, pacc[mt], 0, 0, 0);
    }
  }
  const size_t gm = gaddr(nb, w * 16 + lr);
#pragma unroll
  for (int mt = 0; mt < 4; ++mt) {
    const float4 bias = *(const float4*)(pb + mt * 16 + lg * 4);
    u16x4 u;
    u[0] = f2us(pacc[mt][0] + bias.x); u[1] = f2us(pacc[mt][1] + bias.y);
    u[2] = f2us(pacc[mt][2] + bias.z); u[3] = f2us(pacc[mt][3] + bias.w);
    *(u16x4*)(xlow + gm + mt * 16 + lg * 4) = u;
  }
}

// ------- depthwise 3x3 + gelu + residual -> xconv (bf16, streaming) ---------
__global__ __launch_bounds__(256, 3) void k_dw(const u16t* __restrict__ y1,
    const u16t* __restrict__ xdct, u16t* __restrict__ xconv,
    const float* __restrict__ dwg)
{
  __shared__ __align__(16) u16t y1h[18][18][68];
  __shared__ float dws[64][9];
  const int t = threadIdx.x;
  const int blk = blockIdx.x;
  const int b = blk >> 8, ty = (blk >> 4) & 15, tx = blk & 15;
  for (int e = t; e < 576; e += 256) dws[e / 9][e % 9] = dwg[e];
  // stage y1 tile with zero halo
  for (int s = t; s < 5184; s += 256) {
    const int r2 = s >> 4, c4 = (s & 15) * 4;
    const int iy2 = r2 / 18, ix2 = r2 % 18;
    const int py = ty * 16 + iy2 - 1, px = tx * 16 + ix2 - 1;
    u16x4 u = {0, 0, 0, 0};
    if ((unsigned)py < 256u && (unsigned)px < 256u) {
      const size_t g = ((size_t)((b * 256 + py) * 256 + px)) * 64 + c4;
      u = *(const u16x4*)(y1 + g);
    }
    *(u16x4*)&y1h[iy2][ix2][c4] = u;
  }
  __syncthreads();
  const int iy = t >> 4, ix = t & 15;
  const size_t gpx = ((size_t)((b * 256 + ty * 16 + iy) * 256 + tx * 16 + ix)) * 64;
#pragma unroll
  for (int c4i = 0; c4i < 16; ++c4i) {
    const int c4 = c4i * 4;
    float s0 = 0.f, s1 = 0.f, s2 = 0.f, s3 = 0.f;
#pragma unroll
    for (int dy = 0; dy < 3; ++dy)
#pragma unroll
      for (int dx = 0; dx < 3; ++dx) {
        const u16x4 u = *(const u16x4*)&y1h[iy + dy][ix + dx][c4];
        const int j = dy * 3 + dx;
        s0 = fmaf(us2f(u[0]), dws[c4 + 0][j], s0);
        s1 = fmaf(us2f(u[1]), dws[c4 + 1][j], s1);
        s2 = fmaf(us2f(u[2]), dws[c4 + 2][j], s2);
        s3 = fmaf(us2f(u[3]), dws[c4 + 3][j], s3);
      }
    const u16x4 x = *(const u16x4*)(xdct + gpx + c4);
    u16x4 o;
    o[0] = f2us(gelu(s0) + us2f(x[0])); o[1] = f2us(gelu(s1) + us2f(x[1]));
    o[2] = f2us(gelu(s2) + us2f(x[2])); o[3] = f2us(gelu(s3) + us2f(x[3]));
    *(u16x4*)(xconv + gpx + c4) = o;
  }
}

// ------- c2 GEMM (zero LDS) + gelu + residual + coef combine ----------------
__global__ __launch_bounds__(256, 4) void k_c2(const u16t* __restrict__ xconv,
    u16t* __restrict__ xio, const u16t* __restrict__ xlow,
    const u16t* __restrict__ W2b, const float* __restrict__ coef)
{
  const int t = threadIdx.x, w = t >> 6, l = t & 63;
  const int lr = l & 15, lg = l >> 4;
  const size_t ebase = (size_t)blockIdx.x * 16384;   // 256 px * 64 c
  const int pb0 = (blockIdx.x & 255) * 256;          // pixel base within image
  s16x8 af[4][2];                        // A = W2b[co][ci]
#pragma unroll
  for (int mt = 0; mt < 4; ++mt)
#pragma unroll
    for (int ks = 0; ks < 2; ++ks)
      af[mt][ks] = *(const s16x8*)(W2b + (mt * 16 + lr) * 64 + ks * 32 + lg * 8);
  f32x4 acc[4][4];
#pragma unroll
  for (int i = 0; i < 4; ++i)
#pragma unroll
    for (int j = 0; j < 4; ++j) acc[i][j] = (f32x4){0.f, 0.f, 0.f, 0.f};
#pragma unroll
  for (int nt = 0; nt < 4; ++nt) {
    const int px = w * 64 + nt * 16 + lr;
#pragma unroll
    for (int ks = 0; ks < 2; ++ks) {
      s16x8 bf = *(const s16x8*)(xconv + ebase + (size_t)px * 64 + ks * 32 + lg * 8);
#pragma unroll
      for (int mt = 0; mt < 4; ++mt)
        acc[mt][nt] = __builtin_amdgcn_mfma_f32_16x16x32_bf16(af[mt][ks], bf, acc[mt][nt], 0, 0, 0);
    }
  }
  // epilogue: xh = gelu(c2)+xconv; out = cf*xlow + (1-cf)*xh + xdct
#pragma unroll
  for (int nt = 0; nt < 4; ++nt) {
    const int px = w * 64 + nt * 16 + lr;
    const float cf = coef[pb0 + px];
    const size_t gb = ebase + (size_t)px * 64;
#pragma unroll
    for (int mt = 0; mt < 4; ++mt) {
      const int c0 = mt * 16 + lg * 4;
      const u16x4 xd = *(const u16x4*)(xio + gb + c0);
      const u16x4 xl = *(const u16x4*)(xlow + gb + c0);
      const u16x4 xr = *(const u16x4*)(xconv + gb + c0);
      u16x4 o;
#pragma unroll
      for (int r = 0; r < 4; ++r) {
        const float xh = gelu(acc[mt][nt][r]) + us2f(xr[r]);
        o[r] = f2us(cf * us2f(xl[r]) + (1.0f - cf) * xh + us2f(xd[r]));
      }
      *(u16x4*)(xio + gb + c0) = o;
    }
  }
}

// ----------------------------------------------------------------------------
extern "C" void kernel_launch(void* const* d_in, const int* in_sizes, int n_in,
                              void* d_out, int out_size, void* d_ws, size_t ws_size,
                              hipStream_t stream) {
  const float* x_input = (const float*)d_in[0];
  const float* Wq      = (const float*)d_in[1];
  const float* Wk      = (const float*)d_in[2];
  const float* Wv      = (const float*)d_in[3];
  const float* resc    = (const float*)d_in[4];
  const float* proj_w  = (const float*)d_in[5];
  const float* proj_b  = (const float*)d_in[6];
  const float* c1a_w   = (const float*)d_in[7];
  const float* c1b_w   = (const float*)d_in[8];
  const float* c2_w    = (const float*)d_in[9];
  const float* coef    = (const float*)d_in[10];
  float* out = (float*)d_out;

  char* ws = (char*)d_ws;
  u16t* A   = (u16t*)ws;                       // 33.5 MB
  u16t* Bb  = (u16t*)(ws + 33554432);          // 33.5 MB
  u16t* Mtf = (u16t*)(ws + 67108864);
  u16t* Mti = Mtf + 65536;
  u16t* WqT = Mti + 65536;
  u16t* WkT = WqT + 4096;
  u16t* WvT = WkT + 4096;
  u16t* pwT = WvT + 4096;
  u16t* W1b = pwT + 4096;
  u16t* W2b = W1b + 4096;
  u16t* xlow  = (u16t*)d_out;                  // bf16, first half of d_out
  u16t* xconv = xlow + 16777216;               // bf16, second half of d_out

  k_init<<<dim3(257), dim3(256), 0, stream>>>(Mtf, Mti, WqT, WkT, WvT, pwT, W1b, W2b,
                                              Wq, Wk, Wv, proj_w, c1a_w, c2_w);
  // DCT along W: x -> A
  k_tmfma<false, true><<<dim3(1024), dim3(256), 0, stream>>>(x_input, A, Mtf, 16384, 64);
  // DCT along H: A -> Bb (= xdct)
  k_tmfma<true, true><<<dim3(1024), dim3(256), 0, stream>>>(A, Bb, Mtf, 64, 16384);
  // conv branch part 1: y1 = gelu(conv1x1(xdct)) -> A
  k_conv1<<<dim3(1024), dim3(256), 0, stream>>>(Bb, A, W1b);
  // attention branch: xdct -> x_low (bf16, first half of d_out)
  k_attn<<<dim3(4096), dim3(256), 0, stream>>>(Bb, xlow, WqT, WkT, WvT, pwT, resc, proj_b);
  // depthwise 3x3 + gelu + residual: (y1, xdct) -> xconv
  k_dw<<<dim3(1024), dim3(256), 0, stream>>>(A, Bb, xconv, c1b_w);
  // c2 GEMM + combine -> Bb (in place over xdct)
  k_c2<<<dim3(1024), dim3(256), 0, stream>>>(xconv, Bb, xlow, W2b, coef);
  // IDCT along W: Bb -> A
  k_tmfma<true, true><<<dim3(1024), dim3(256), 0, stream>>>(Bb, A, Mti, 16384, 64);
  // IDCT along H: A -> out (f32, final NHWC)
  k_tmfma<true, false><<<dim3(1024), dim3(256), 0, stream>>>(A, out, Mti, 64, 16384);
}